// Round 9
// baseline (101.540 us; speedup 1.0000x reference)
//
#include <hip/hip_runtime.h>
#include <hip/hip_bf16.h>
#include <math.h>

#define NC 195                 // number of countries
#define ROWS_PER_CHUNK 16      // per-iteration tile: 16 rows = 780 float4 = 12480 B
#define CHUNKS_PER_BLOCK 8     // block processes 128 rows total
#define BLOCK_ROWS (ROWS_PER_CHUNK * CHUNKS_PER_BLOCK)   // 128
#define F4_PER_CHUNK (ROWS_PER_CHUNK * NC / 4)           // 780

// ---- DPP 16-lane butterfly (VALU pipe; replaces LDS-pipe __shfl_xor) ----
// level pairings: xor1 (quad_perm[1,0,3,2]=0xB1), xor2 (quad_perm[2,3,0,1]=0x4E),
// cross-quad (row_half_mirror=0x141), cross-oct (row_mirror=0x140).
// Any disjoint involution pairing is valid for (max,min-idx) / sum reduction.
template<int CTRL>
__device__ __forceinline__ float dpp_f(float v) {
    int i = __float_as_int(v);
    return __int_as_float(__builtin_amdgcn_update_dpp(i, i, CTRL, 0xF, 0xF, false));
}
template<int CTRL>
__device__ __forceinline__ int dpp_i(int v) {
    return __builtin_amdgcn_update_dpp(v, v, CTRL, 0xF, 0xF, false);
}

__device__ __forceinline__ float hav_scaled(float lat1, float lon1, float lat2, float lon2) {
    const float d2r = 0.017453292519943295f;
    lat1 *= d2r; lon1 *= d2r; lat2 *= d2r; lon2 *= d2r;
    float sdlat = sinf(0.5f * (lat2 - lat1));
    float sdlon = sinf(0.5f * (lon2 - lon1));
    float a = sdlat * sdlat + cosf(lat1) * cosf(lat2) * sdlon * sdlon;
    a = fminf(fmaxf(a, 0.0f), 1.0f);
    return (2.0f * 6371.0f / 500.0f) * asinf(sqrtf(a));  // 2*R*asin(sqrt(a))/500
}

// Kernel A: 195x195 pairwise scaled distances; zeroes the arrival counter
// (stream order guarantees counter==0 before main_kernel each call)
__global__ void dist_kernel(const float* __restrict__ coords, float* __restrict__ distm,
                            unsigned int* __restrict__ counter) {
    if (blockIdx.x == 0 && threadIdx.x == 0) *counter = 0u;
    int idx = blockIdx.x * 256 + threadIdx.x;
    if (idx >= NC * NC) return;
    int i = idx / NC;
    int j = idx - i * NC;
    distm[idx] = hav_scaled(coords[2 * i], coords[2 * i + 1],
                            coords[2 * j], coords[2 * j + 1]);
}

// Kernel B: r7-proven float4->LDS staging + register async prefetch of next
// chunk; 16-lane groups, DPP butterflies; fused last-block final reduce (r8-proven).
__global__ __launch_bounds__(256) void main_kernel(const float4* __restrict__ logits4,
                                                   const int* __restrict__ target,
                                                   const float* __restrict__ distm,
                                                   float* __restrict__ partials,
                                                   unsigned int* __restrict__ counter,
                                                   float inv_b,
                                                   float* __restrict__ out) {
    __shared__ float lds[ROWS_PER_CHUNK * NC];   // 12480 B, single buffer
    __shared__ int tgt[BLOCK_ROWS];
    __shared__ float wpart[16];
    __shared__ bool amLast;
    const int t = threadIdx.x;
    float4* lds4 = (float4*)lds;

    const long long row0 = (long long)blockIdx.x * BLOCK_ROWS;
    if (t < BLOCK_ROWS) tgt[t] = target[row0 + t];   // one coalesced 128-int read

    const long long base4 = (long long)blockIdx.x * CHUNKS_PER_BLOCK * F4_PER_CHUNK;

    // prologue: stage chunk 0
    float4 n0 = logits4[base4 + t];
    float4 n1 = logits4[base4 + t + 256];
    float4 n2 = logits4[base4 + t + 512];
    float4 n3;
    if (t < F4_PER_CHUNK - 768) n3 = logits4[base4 + t + 768];
    lds4[t] = n0; lds4[t + 256] = n1; lds4[t + 512] = n2;
    if (t < F4_PER_CHUNK - 768) lds4[t + 768] = n3;
    __syncthreads();

    const int u = t & 15;          // lane within 16-lane row group
    const int r = t >> 4;          // row group (0..15)
    const float* __restrict__ rowp = lds + r * NC;
    float acc = 0.0f;

    for (int i = 0; i < CHUNKS_PER_BLOCK; ++i) {
        const bool has_next = (i + 1 < CHUNKS_PER_BLOCK);
        if (has_next) {            // issue next chunk's loads under compute
            const long long nb = base4 + (long long)(i + 1) * F4_PER_CHUNK;
            n0 = logits4[nb + t];
            n1 = logits4[nb + t + 256];
            n2 = logits4[nb + t + 512];
            if (t < F4_PER_CHUNK - 768) n3 = logits4[nb + t + 768];
        }

        float x[13];
        #pragma unroll
        for (int k = 0; k < 12; ++k) x[k] = rowp[u + 16 * k];
        x[12] = (u < 3) ? rowp[192 + u] : -INFINITY;

        // lane-local max + argmax (first occurrence)
        float m = x[0]; int mi = u;
        #pragma unroll
        for (int k = 1; k < 13; ++k) {
            if (x[k] > m) { m = x[k]; mi = u + 16 * k; }
        }
        // DPP butterfly: (max, min-index) over the 16-lane group
        {
            float om; int oi;
            om = dpp_f<0xB1>(m);  oi = dpp_i<0xB1>(mi);
            if (om > m || (om == m && oi < mi)) { m = om; mi = oi; }
            om = dpp_f<0x4E>(m);  oi = dpp_i<0x4E>(mi);
            if (om > m || (om == m && oi < mi)) { m = om; mi = oi; }
            om = dpp_f<0x141>(m); oi = dpp_i<0x141>(mi);
            if (om > m || (om == m && oi < mi)) { m = om; mi = oi; }
            om = dpp_f<0x140>(m); oi = dpp_i<0x140>(mi);
            if (om > m || (om == m && oi < mi)) { m = om; mi = oi; }
        }
        float s = 0.0f;
        #pragma unroll
        for (int k = 0; k < 13; ++k) s += __expf(x[k] - m);
        s += dpp_f<0xB1>(s);
        s += dpp_f<0x4E>(s);
        s += dpp_f<0x141>(s);
        s += dpp_f<0x140>(s);

        if (u == 0) {
            int tg = tgt[i * ROWS_PER_CHUNK + r];
            float ce = (m + __logf(s)) - rowp[tg];   // lse - x_target (LDS)
            acc += ce + distm[mi * NC + tg];         // distm pre-scaled by 1/500
        }
        __syncthreads();                // all groups done reading chunk i
        if (has_next) {
            lds4[t] = n0; lds4[t + 256] = n1; lds4[t + 512] = n2;
            if (t < F4_PER_CHUNK - 768) lds4[t + 768] = n3;
            __syncthreads();            // chunk i+1 visible
        }
    }

    if (u == 0) wpart[r] = acc;
    __syncthreads();
    if (t == 0) {
        float v = 0.0f;
        #pragma unroll
        for (int j = 0; j < 16; ++j) v += wpart[j];
        partials[blockIdx.x] = v;
        __threadfence();                             // release
        unsigned int old = atomicAdd(counter, 1u);   // device-scope
        amLast = (old == gridDim.x - 1);
    }
    __syncthreads();
    if (amLast) {                                    // fused final reduce (r8-proven)
        __threadfence();                             // acquire
        float sum = 0.0f;
        #pragma unroll
        for (int j = 0; j < 8; ++j) sum += partials[t + 256 * j];  // fixed order
        #pragma unroll
        for (int off = 32; off > 0; off >>= 1) sum += __shfl_xor(sum, off);
        if ((t & 63) == 0) wpart[t >> 6] = sum;
        __syncthreads();
        if (t == 0) out[0] = (wpart[0] + wpart[1] + wpart[2] + wpart[3]) * inv_b;
    }
}

extern "C" void kernel_launch(void* const* d_in, const int* in_sizes, int n_in,
                              void* d_out, int out_size, void* d_ws, size_t ws_size,
                              hipStream_t stream) {
    const float* logits = (const float*)d_in[0];
    const int*   target = (const int*)d_in[1];
    const float* coords = (const float*)d_in[2];
    float* out = (float*)d_out;

    const int B = in_sizes[1];                    // 262144
    const int n_blocks = B / BLOCK_ROWS;          // 2048 = 8 blocks/CU exactly

    // ws layout: partials[2048] | counter (16B slot) | distm[195*195]
    float* partials = (float*)d_ws;
    unsigned int* counter = (unsigned int*)(partials + n_blocks);
    float* distm = (float*)(partials + n_blocks + 4);

    dist_kernel<<<(NC * NC + 255) / 256, 256, 0, stream>>>(coords, distm, counter);
    main_kernel<<<n_blocks, 256, 0, stream>>>((const float4*)logits, target, distm,
                                              partials, counter, 1.0f / (float)B, out);
}

// Round 10
// 43.774 us; speedup vs baseline: 2.3197x; 2.3197x over previous
//
#include <hip/hip_runtime.h>
#include <hip/hip_bf16.h>
#include <math.h>

#define NC 195                 // number of countries
#define ROWS_PER_CHUNK 16      // per-iteration tile: 16 rows = 780 float4 = 12480 B
#define CHUNKS_PER_BLOCK 8     // block processes 128 rows total
#define BLOCK_ROWS (ROWS_PER_CHUNK * CHUNKS_PER_BLOCK)   // 128
#define F4_PER_CHUNK (ROWS_PER_CHUNK * NC / 4)           // 780

// ---- DPP 16-lane butterfly (VALU pipe; replaces LDS-pipe __shfl_xor) ----
// 0xB1 quad_perm[1,0,3,2] (xor1), 0x4E quad_perm[2,3,0,1] (xor2),
// 0x141 row_half_mirror (pairs quad0<->quad1 in each 8), 0x140 row_mirror
// (pairs oct0<->oct1 in each 16). Valid: at each level the sub-groups are
// internally uniform, so any bijective pairing reduces correctly.
template<int CTRL>
__device__ __forceinline__ float dpp_f(float v) {
    int i = __float_as_int(v);
    return __int_as_float(__builtin_amdgcn_update_dpp(i, i, CTRL, 0xF, 0xF, false));
}
template<int CTRL>
__device__ __forceinline__ int dpp_i(int v) {
    return __builtin_amdgcn_update_dpp(v, v, CTRL, 0xF, 0xF, false);
}

__device__ __forceinline__ float hav_scaled(float lat1, float lon1, float lat2, float lon2) {
    const float d2r = 0.017453292519943295f;
    lat1 *= d2r; lon1 *= d2r; lat2 *= d2r; lon2 *= d2r;
    float sdlat = sinf(0.5f * (lat2 - lat1));
    float sdlon = sinf(0.5f * (lon2 - lon1));
    float a = sdlat * sdlat + cosf(lat1) * cosf(lat2) * sdlon * sdlon;
    a = fminf(fmaxf(a, 0.0f), 1.0f);
    return (2.0f * 6371.0f / 500.0f) * asinf(sqrtf(a));  // 2*R*asin(sqrt(a))/500
}

// Kernel A: 195x195 pairwise scaled distances (dist[i][j], i=pred, j=target)
__global__ void dist_kernel(const float* __restrict__ coords, float* __restrict__ distm) {
    int idx = blockIdx.x * 256 + threadIdx.x;
    if (idx >= NC * NC) return;
    int i = idx / NC;
    int j = idx - i * NC;
    distm[idx] = hav_scaled(coords[2 * i], coords[2 * i + 1],
                            coords[2 * j], coords[2 * j + 1]);
}

// Kernel B: EXACT r7 structure (45.6us proven) with ONE change:
// shfl_xor butterflies -> DPP row ops. No fences, no atomics.
__global__ __launch_bounds__(256) void main_kernel(const float4* __restrict__ logits4,
                                                   const int* __restrict__ target,
                                                   const float* __restrict__ distm,
                                                   float* __restrict__ partials) {
    __shared__ float lds[ROWS_PER_CHUNK * NC];   // 12480 B, single buffer
    __shared__ int tgt[BLOCK_ROWS];
    __shared__ float wpart[16];
    const int t = threadIdx.x;
    float4* lds4 = (float4*)lds;

    const long long row0 = (long long)blockIdx.x * BLOCK_ROWS;
    if (t < BLOCK_ROWS) tgt[t] = target[row0 + t];   // one coalesced 128-int read

    const long long base4 = (long long)blockIdx.x * CHUNKS_PER_BLOCK * F4_PER_CHUNK;

    // prologue: stage chunk 0
    float4 n0 = logits4[base4 + t];
    float4 n1 = logits4[base4 + t + 256];
    float4 n2 = logits4[base4 + t + 512];
    float4 n3;
    if (t < F4_PER_CHUNK - 768) n3 = logits4[base4 + t + 768];
    lds4[t] = n0; lds4[t + 256] = n1; lds4[t + 512] = n2;
    if (t < F4_PER_CHUNK - 768) lds4[t + 768] = n3;
    __syncthreads();

    const int u = t & 15;          // lane within 16-lane row group
    const int r = t >> 4;          // row group (0..15)
    const float* __restrict__ rowp = lds + r * NC;
    float acc = 0.0f;

    for (int i = 0; i < CHUNKS_PER_BLOCK; ++i) {
        const bool has_next = (i + 1 < CHUNKS_PER_BLOCK);
        if (has_next) {            // issue next chunk's loads under compute
            const long long nb = base4 + (long long)(i + 1) * F4_PER_CHUNK;
            n0 = logits4[nb + t];
            n1 = logits4[nb + t + 256];
            n2 = logits4[nb + t + 512];
            if (t < F4_PER_CHUNK - 768) n3 = logits4[nb + t + 768];
        }

        float x[13];
        #pragma unroll
        for (int k = 0; k < 12; ++k) x[k] = rowp[u + 16 * k];
        x[12] = (u < 3) ? rowp[192 + u] : -INFINITY;

        // lane-local max + argmax (first occurrence)
        float m = x[0]; int mi = u;
        #pragma unroll
        for (int k = 1; k < 13; ++k) {
            if (x[k] > m) { m = x[k]; mi = u + 16 * k; }
        }
        // DPP butterfly: (max, min-index) over the 16-lane group
        {
            float om; int oi;
            om = dpp_f<0xB1>(m);  oi = dpp_i<0xB1>(mi);
            if (om > m || (om == m && oi < mi)) { m = om; mi = oi; }
            om = dpp_f<0x4E>(m);  oi = dpp_i<0x4E>(mi);
            if (om > m || (om == m && oi < mi)) { m = om; mi = oi; }
            om = dpp_f<0x141>(m); oi = dpp_i<0x141>(mi);
            if (om > m || (om == m && oi < mi)) { m = om; mi = oi; }
            om = dpp_f<0x140>(m); oi = dpp_i<0x140>(mi);
            if (om > m || (om == m && oi < mi)) { m = om; mi = oi; }
        }
        float s = 0.0f;
        #pragma unroll
        for (int k = 0; k < 13; ++k) s += __expf(x[k] - m);
        s += dpp_f<0xB1>(s);
        s += dpp_f<0x4E>(s);
        s += dpp_f<0x141>(s);
        s += dpp_f<0x140>(s);

        if (u == 0) {
            int tg = tgt[i * ROWS_PER_CHUNK + r];
            float ce = (m + __logf(s)) - rowp[tg];   // lse - x_target (LDS)
            acc += ce + distm[mi * NC + tg];         // distm pre-scaled by 1/500
        }
        __syncthreads();                // all groups done reading chunk i
        if (has_next) {
            lds4[t] = n0; lds4[t + 256] = n1; lds4[t + 512] = n2;
            if (t < F4_PER_CHUNK - 768) lds4[t + 768] = n3;
            __syncthreads();            // chunk i+1 visible
        }
    }

    if (u == 0) wpart[r] = acc;
    __syncthreads();
    if (t == 0) {
        float v = 0.0f;
        #pragma unroll
        for (int j = 0; j < 16; ++j) v += wpart[j];
        partials[blockIdx.x] = v;
    }
}

// Kernel C: single block reduces 2048 partials, writes mean (r7-proven)
__global__ __launch_bounds__(1024) void reduce_kernel(const float* __restrict__ partials,
                                                      float inv_b, float* __restrict__ out) {
    float s = partials[threadIdx.x] + partials[threadIdx.x + 1024];
    #pragma unroll
    for (int off = 32; off > 0; off >>= 1) s += __shfl_xor(s, off);
    __shared__ float ws[16];
    if ((threadIdx.x & 63) == 0) ws[threadIdx.x >> 6] = s;
    __syncthreads();
    if (threadIdx.x == 0) {
        float tot = 0.0f;
        #pragma unroll
        for (int w = 0; w < 16; ++w) tot += ws[w];
        out[0] = tot * inv_b;
    }
}

extern "C" void kernel_launch(void* const* d_in, const int* in_sizes, int n_in,
                              void* d_out, int out_size, void* d_ws, size_t ws_size,
                              hipStream_t stream) {
    const float* logits = (const float*)d_in[0];
    const int*   target = (const int*)d_in[1];
    const float* coords = (const float*)d_in[2];
    float* out = (float*)d_out;

    const int B = in_sizes[1];               // 262144
    const int n_blocks = B / BLOCK_ROWS;     // 2048 = 8 blocks/CU exactly

    // ws layout: partials[2048] | distm[195*195]
    float* partials = (float*)d_ws;
    float* distm = partials + n_blocks;

    dist_kernel<<<(NC * NC + 255) / 256, 256, 0, stream>>>(coords, distm);
    main_kernel<<<n_blocks, 256, 0, stream>>>((const float4*)logits, target, distm, partials);
    reduce_kernel<<<1, 1024, 0, stream>>>(partials, 1.0f / (float)B, out);
}